// Round 1
// baseline (265.621 us; speedup 1.0000x reference)
//
#include <hip/hip_runtime.h>
#include <hip/hip_bf16.h>
#include <stdint.h>

// ---------------------------------------------------------------------------
// Cosine similarity: C[n][m] = <z_n/||z_n||, cm_m/||cm_m||>
// M=32768 rows z, Ncls=1001 rows cm, K=512, out fp32 [M][Ncls].
// Pass 1: normalize rows -> bf16 in d_ws (zn: M*512, bn: Npad*512 zero-padded).
// Pass 2: bf16 MFMA GEMM (A * B^T), 128x128 tile, BK=32, global_load_lds x16.
// Workspace need: (32768+1024)*512*2 B = 33 MB.
// ---------------------------------------------------------------------------

typedef short short8 __attribute__((ext_vector_type(8)));
typedef float f32x4 __attribute__((ext_vector_type(4)));

#define KDIM 512

__device__ __forceinline__ unsigned short f2bf(float f) {
  uint32_t u = __float_as_uint(f);
  u += 0x7FFFu + ((u >> 16) & 1u);   // round-to-nearest-even
  return (unsigned short)(u >> 16);
}

// One wave per row. Rows [0,M) come from z; rows [M, M+Npad) map to cm rows
// (r >= Ncls writes zeros so the GEMM needs no B-side bounds checks).
__global__ __launch_bounds__(256) void normalize_rows_kernel(
    const float* __restrict__ z, const float* __restrict__ cm,
    unsigned short* __restrict__ zn, unsigned short* __restrict__ bn,
    int M, int Ncls, int Npad) {
  int gr = blockIdx.x * 4 + (threadIdx.x >> 6);
  int lane = threadIdx.x & 63;

  const float* src;
  unsigned short* dst;
  bool zero = false;
  if (gr < M) {
    src = z + (size_t)gr * KDIM;
    dst = zn + (size_t)gr * KDIM;
  } else {
    int r = gr - M;
    if (r >= Npad) return;
    dst = bn + (size_t)r * KDIM;
    zero = (r >= Ncls);
    src = cm + (size_t)(zero ? 0 : r) * KDIM;
  }

  if (zero) {
    uint4 zv = make_uint4(0u, 0u, 0u, 0u);
    *(uint4*)(dst + lane * 8) = zv;
    return;
  }

  const float4* s4 = (const float4*)src;
  float4 x0 = s4[lane * 2];
  float4 x1 = s4[lane * 2 + 1];
  float s = x0.x * x0.x + x0.y * x0.y + x0.z * x0.z + x0.w * x0.w +
            x1.x * x1.x + x1.y * x1.y + x1.z * x1.z + x1.w * x1.w;
#pragma unroll
  for (int off = 32; off > 0; off >>= 1) s += __shfl_xor(s, off, 64);
  float scale = 1.0f / fmaxf(sqrtf(s), 1e-8f);

  union { unsigned short u[8]; uint4 v; } pk;
  pk.u[0] = f2bf(x0.x * scale); pk.u[1] = f2bf(x0.y * scale);
  pk.u[2] = f2bf(x0.z * scale); pk.u[3] = f2bf(x0.w * scale);
  pk.u[4] = f2bf(x1.x * scale); pk.u[5] = f2bf(x1.y * scale);
  pk.u[6] = f2bf(x1.z * scale); pk.u[7] = f2bf(x1.w * scale);
  *(uint4*)(dst + lane * 8) = pk.v;
}

// C = A * B^T. A: [M][512] bf16 bits, B: [Npad][512] bf16 bits, C: [M][Ncls] f32.
// 128x128 block tile, 4 waves in 2x2, each wave 64x64 = 4x4 MFMA 16x16x32.
__global__ __launch_bounds__(256) void gemm_bt_kernel(
    const unsigned short* __restrict__ A,
    const unsigned short* __restrict__ B,
    float* __restrict__ C, int M, int Ncls) {
  __shared__ unsigned short As[128 * 32];
  __shared__ unsigned short Bs[128 * 32];

  const int tid = threadIdx.x;
  const int wave = tid >> 6;
  const int lane = tid & 63;
  const int m0 = blockIdx.y * 128;
  const int n0 = blockIdx.x * 128;
  const int wm = (wave & 1) * 64;   // wave's M offset in tile
  const int wn = (wave >> 1) * 64;  // wave's N offset in tile

  // Staging geometry: per global_load_lds(16B), a wave covers 16 rows x 32 cols.
  // LDS dest must be wave-uniform base + lane*16 -> unpadded [128][32] layout.
  const int s_r = lane >> 2;        // row within 16-row chunk
  const int s_c = (lane & 3) * 8;   // element col offset (0,8,16,24)
  const int c0 = wave * 2;          // this wave's first chunk (2 chunks/wave)

  const unsigned short* Ag0 = A + (size_t)(m0 + c0 * 16 + s_r) * KDIM + s_c;
  const unsigned short* Ag1 = A + (size_t)(m0 + (c0 + 1) * 16 + s_r) * KDIM + s_c;
  const unsigned short* Bg0 = B + (size_t)(n0 + c0 * 16 + s_r) * KDIM + s_c;
  const unsigned short* Bg1 = B + (size_t)(n0 + (c0 + 1) * 16 + s_r) * KDIM + s_c;
  unsigned short* Al0 = &As[c0 * 512 + lane * 8];
  unsigned short* Al1 = &As[(c0 + 1) * 512 + lane * 8];
  unsigned short* Bl0 = &Bs[c0 * 512 + lane * 8];
  unsigned short* Bl1 = &Bs[(c0 + 1) * 512 + lane * 8];

  const int fr = lane & 15;         // fragment row (m or n)
  const int fk = (lane >> 4) * 8;   // fragment k offset

  f32x4 acc[4][4] = {};

  for (int k0 = 0; k0 < KDIM; k0 += 32) {
    __syncthreads();  // previous iteration's LDS reads complete
    __builtin_amdgcn_global_load_lds(
        (const __attribute__((address_space(1))) void*)(Ag0 + k0),
        (__attribute__((address_space(3))) void*)Al0, 16, 0, 0);
    __builtin_amdgcn_global_load_lds(
        (const __attribute__((address_space(1))) void*)(Ag1 + k0),
        (__attribute__((address_space(3))) void*)Al1, 16, 0, 0);
    __builtin_amdgcn_global_load_lds(
        (const __attribute__((address_space(1))) void*)(Bg0 + k0),
        (__attribute__((address_space(3))) void*)Bl0, 16, 0, 0);
    __builtin_amdgcn_global_load_lds(
        (const __attribute__((address_space(1))) void*)(Bg1 + k0),
        (__attribute__((address_space(3))) void*)Bl1, 16, 0, 0);
    __syncthreads();  // drains vmcnt(0): staged tiles visible

    short8 a[4], b[4];
#pragma unroll
    for (int mi = 0; mi < 4; ++mi)
      a[mi] = *(const short8*)&As[(wm + mi * 16 + fr) * 32 + fk];
#pragma unroll
    for (int ni = 0; ni < 4; ++ni)
      b[ni] = *(const short8*)&Bs[(wn + ni * 16 + fr) * 32 + fk];

#pragma unroll
    for (int mi = 0; mi < 4; ++mi)
#pragma unroll
      for (int ni = 0; ni < 4; ++ni)
        acc[mi][ni] = __builtin_amdgcn_mfma_f32_16x16x32_bf16(
            a[mi], b[ni], acc[mi][ni], 0, 0, 0);
  }

  // C/D layout: col = lane&15 (n), row = (lane>>4)*4 + j (m).
  const int cn = lane & 15;
  const int cr = (lane >> 4) * 4;
#pragma unroll
  for (int mi = 0; mi < 4; ++mi) {
#pragma unroll
    for (int ni = 0; ni < 4; ++ni) {
      int n = n0 + wn + ni * 16 + cn;
      if (n < Ncls) {
        size_t base = (size_t)(m0 + wm + mi * 16 + cr) * (size_t)Ncls + n;
#pragma unroll
        for (int j = 0; j < 4; ++j)
          C[base + (size_t)j * Ncls] = acc[mi][ni][j];
      }
    }
  }
}

extern "C" void kernel_launch(void* const* d_in, const int* in_sizes, int n_in,
                              void* d_out, int out_size, void* d_ws, size_t ws_size,
                              hipStream_t stream) {
  const float* z  = (const float*)d_in[0];
  const float* cm = (const float*)d_in[1];
  float* out = (float*)d_out;

  const int M    = in_sizes[0] / KDIM;                 // 32768
  const int Ncls = in_sizes[1] / KDIM;                 // 1001
  const int Npad = ((Ncls + 127) / 128) * 128;         // 1024

  unsigned short* zn = (unsigned short*)d_ws;
  unsigned short* bn = zn + (size_t)M * KDIM;

  int nblk = (M + Npad + 3) / 4;  // one wave per row, 4 waves per block
  normalize_rows_kernel<<<nblk, 256, 0, stream>>>(z, cm, zn, bn, M, Ncls, Npad);

  dim3 grid(Npad / 128, M / 128);
  gemm_bt_kernel<<<grid, 256, 0, stream>>>(zn, bn, out, M, Ncls);
}

// Round 2
// 255.537 us; speedup vs baseline: 1.0395x; 1.0395x over previous
//
#include <hip/hip_runtime.h>
#include <hip/hip_bf16.h>
#include <stdint.h>

// ---------------------------------------------------------------------------
// Cosine similarity: C[n][m] = <z_n/||z_n||, cm_m/||cm_m||>
// M=32768 rows z, Ncls=1001 rows cm, K=512, out fp32 [M][Ncls].
// Pass 1: normalize rows -> bf16 in d_ws (zn: M*512, bn: Npad*512 zero-padded).
// Pass 2: bf16 MFMA GEMM (A * B^T), 128x128 tile, BK=64, 32x32x16 MFMA,
//         global_load_lds x16 with XOR-swizzled LDS layout (conflict-free
//         ds_read_b128: swizzle applied to the GLOBAL source address since
//         global_load_lds dest must be uniform-base + lane*16).
// Workspace need: (32768+1024)*512*2 B = 33 MB.
// ---------------------------------------------------------------------------

typedef short short8 __attribute__((ext_vector_type(8)));
typedef float f32x16 __attribute__((ext_vector_type(16)));

#define KDIM 512
#define BK 64

__device__ __forceinline__ unsigned short f2bf(float f) {
  uint32_t u = __float_as_uint(f);
  u += 0x7FFFu + ((u >> 16) & 1u);   // round-to-nearest-even
  return (unsigned short)(u >> 16);
}

// One wave per row; fully coalesced (lane-adjacent float4 reads).
// Rows [0,M) from z; rows [M, M+Npad) map to cm (r >= Ncls writes zeros).
__global__ __launch_bounds__(256) void normalize_rows_kernel(
    const float* __restrict__ z, const float* __restrict__ cm,
    unsigned short* __restrict__ zn, unsigned short* __restrict__ bn,
    int M, int Ncls, int Npad) {
  int gr = blockIdx.x * 4 + (threadIdx.x >> 6);
  int lane = threadIdx.x & 63;

  const float* src;
  unsigned short* dst;
  bool zero = false;
  if (gr < M) {
    src = z + (size_t)gr * KDIM;
    dst = zn + (size_t)gr * KDIM;
  } else {
    int r = gr - M;
    if (r >= Npad) return;
    dst = bn + (size_t)r * KDIM;
    zero = (r >= Ncls);
    src = cm + (size_t)(zero ? 0 : r) * KDIM;
  }

  if (zero) {
    uint2 zv = make_uint2(0u, 0u);
    *(uint2*)(dst + lane * 4) = zv;
    *(uint2*)(dst + 256 + lane * 4) = zv;
    return;
  }

  const float4* s4 = (const float4*)src;
  float4 x0 = s4[lane];        // elements [4*lane, 4*lane+4)
  float4 x1 = s4[lane + 64];   // elements [256+4*lane, ...)
  float s = x0.x * x0.x + x0.y * x0.y + x0.z * x0.z + x0.w * x0.w +
            x1.x * x1.x + x1.y * x1.y + x1.z * x1.z + x1.w * x1.w;
#pragma unroll
  for (int off = 32; off > 0; off >>= 1) s += __shfl_xor(s, off, 64);
  float scale = 1.0f / fmaxf(sqrtf(s), 1e-8f);

  union { unsigned short u[4]; uint2 v; } p0, p1;
  p0.u[0] = f2bf(x0.x * scale); p0.u[1] = f2bf(x0.y * scale);
  p0.u[2] = f2bf(x0.z * scale); p0.u[3] = f2bf(x0.w * scale);
  p1.u[0] = f2bf(x1.x * scale); p1.u[1] = f2bf(x1.y * scale);
  p1.u[2] = f2bf(x1.z * scale); p1.u[3] = f2bf(x1.w * scale);
  *(uint2*)(dst + lane * 4) = p0.v;
  *(uint2*)(dst + 256 + lane * 4) = p1.v;
}

// C = A * B^T. A: [M][512] bf16 bits, B: [Npad][512] bf16 bits, C: [M][Ncls] f32.
// 128x128 block tile, 4 waves in 2x2, each wave 64x64 = 2x2 MFMA 32x32x16.
// LDS tiles [128 rows][8 units of 16B], unit' = unit ^ (row & 7) swizzle.
__global__ __launch_bounds__(256) void gemm_bt_kernel(
    const unsigned short* __restrict__ A,
    const unsigned short* __restrict__ B,
    float* __restrict__ C, int M, int Ncls) {
  __shared__ unsigned short As[128 * BK];
  __shared__ unsigned short Bs[128 * BK];

  const int tid = threadIdx.x;
  const int wave = tid >> 6;
  const int lane = tid & 63;
  const int m0 = blockIdx.y * 128;
  const int n0 = blockIdx.x * 128;
  const int wm = (wave & 1) * 64;   // wave's M offset in tile
  const int wn = (wave >> 1) * 64;  // wave's N offset in tile

  // ---- staging geometry --------------------------------------------------
  // LDS slot s (16B units): chunk = 64 slots = 8 rows x 8 units. Per chunk,
  // lane l -> row = l>>3, lds unit = l&7. Source global unit = (l&7)^((l>>3)&7)
  // so that LDS holds unit' = u ^ (row&7).
  const int l3 = lane >> 3;                      // row within 8-row chunk
  const int su = (lane & 7) ^ (l3 & 7);          // source 16B-unit (0..7)

  const unsigned short* Agp[4];
  const unsigned short* Bgp[4];
  unsigned short* Alp[4];
  unsigned short* Blp[4];
#pragma unroll
  for (int c = 0; c < 4; ++c) {
    int ch = wave * 4 + c;                       // chunk 0..15, rows ch*8..+8
    Agp[c] = A + (size_t)(m0 + ch * 8 + l3) * KDIM + su * 8;
    Bgp[c] = B + (size_t)(n0 + ch * 8 + l3) * KDIM + su * 8;
    Alp[c] = &As[ch * 512 + lane * 8];           // 64 contiguous 16B slots
    Blp[c] = &Bs[ch * 512 + lane * 8];
  }

  // ---- fragment-read geometry -------------------------------------------
  const int fm = lane & 31;        // row within 32-row frag (A: m, B: n)
  const int kh = lane >> 5;        // k-half (0/1) -> 8-elem unit select
  const int fx = fm & 7;           // row phase for the XOR swizzle

  f32x16 acc[2][2] = {};

  for (int k0 = 0; k0 < KDIM; k0 += BK) {
    __syncthreads();  // previous iteration's LDS reads complete
#pragma unroll
    for (int c = 0; c < 4; ++c)
      __builtin_amdgcn_global_load_lds(
          (const __attribute__((address_space(1))) void*)(Agp[c] + k0),
          (__attribute__((address_space(3))) void*)Alp[c], 16, 0, 0);
#pragma unroll
    for (int c = 0; c < 4; ++c)
      __builtin_amdgcn_global_load_lds(
          (const __attribute__((address_space(1))) void*)(Bgp[c] + k0),
          (__attribute__((address_space(3))) void*)Blp[c], 16, 0, 0);
    __syncthreads();  // staged tiles visible

#pragma unroll
    for (int ks = 0; ks < 4; ++ks) {            // 4 k-steps of 16 within BK
      int u = ((ks << 1) | kh) ^ fx;            // swizzled unit
      short8 a0 = *(const short8*)&As[(wm + fm) * BK + u * 8];
      short8 a1 = *(const short8*)&As[(wm + 32 + fm) * BK + u * 8];
      short8 b0 = *(const short8*)&Bs[(wn + fm) * BK + u * 8];
      short8 b1 = *(const short8*)&Bs[(wn + 32 + fm) * BK + u * 8];
      acc[0][0] = __builtin_amdgcn_mfma_f32_32x32x16_bf16(a0, b0, acc[0][0], 0, 0, 0);
      acc[0][1] = __builtin_amdgcn_mfma_f32_32x32x16_bf16(a0, b1, acc[0][1], 0, 0, 0);
      acc[1][0] = __builtin_amdgcn_mfma_f32_32x32x16_bf16(a1, b0, acc[1][0], 0, 0, 0);
      acc[1][1] = __builtin_amdgcn_mfma_f32_32x32x16_bf16(a1, b1, acc[1][1], 0, 0, 0);
    }
  }

  // C/D layout (32x32): col = lane&31, row = (reg&3) + 8*(reg>>2) + 4*(lane>>5)
  const int cn = lane & 31;
  const int ch4 = (lane >> 5) * 4;
#pragma unroll
  for (int mi = 0; mi < 2; ++mi) {
#pragma unroll
    for (int ni = 0; ni < 2; ++ni) {
      int n = n0 + wn + ni * 32 + cn;
      if (n < Ncls) {
        size_t base = (size_t)(m0 + wm + mi * 32 + ch4) * (size_t)Ncls + n;
#pragma unroll
        for (int r = 0; r < 16; ++r) {
          int row = (r & 3) + 8 * (r >> 2);
          C[base + (size_t)row * Ncls] = acc[mi][ni][r];
        }
      }
    }
  }
}

extern "C" void kernel_launch(void* const* d_in, const int* in_sizes, int n_in,
                              void* d_out, int out_size, void* d_ws, size_t ws_size,
                              hipStream_t stream) {
  const float* z  = (const float*)d_in[0];
  const float* cm = (const float*)d_in[1];
  float* out = (float*)d_out;

  const int M    = in_sizes[0] / KDIM;                 // 32768
  const int Ncls = in_sizes[1] / KDIM;                 // 1001
  const int Npad = ((Ncls + 127) / 128) * 128;         // 1024

  unsigned short* zn = (unsigned short*)d_ws;
  unsigned short* bn = zn + (size_t)M * KDIM;

  int nblk = (M + Npad + 3) / 4;  // one wave per row, 4 waves per block
  normalize_rows_kernel<<<nblk, 256, 0, stream>>>(z, cm, zn, bn, M, Ncls, Npad);

  dim3 grid(Npad / 128, M / 128);
  gemm_bt_kernel<<<grid, 256, 0, stream>>>(zn, bn, out, M, Ncls);
}

// Round 3
// 239.426 us; speedup vs baseline: 1.1094x; 1.0673x over previous
//
#include <hip/hip_runtime.h>
#include <hip/hip_bf16.h>
#include <stdint.h>

// ---------------------------------------------------------------------------
// Cosine similarity: C[n][m] = <z_n/||z_n||, cm_m/||cm_m||>
// M=32768 rows z, Ncls=1001 rows cm, K=512, out fp32 [M][Ncls].
// Pass 1: normalize rows -> bf16 in d_ws (zn: M*512, bn: Npad*512 zero-padded).
// Pass 2: bf16 MFMA GEMM (A * B^T), 128M x 256N tile, 512 thr (8 waves of
//         64x64 = 2x2 mfma_32x32x16), BK=64, global_load_lds x16 with
//         XOR-swizzled LDS (swizzle applied to the GLOBAL source address
//         since global_load_lds dest must be uniform-base + lane*16).
// BN=256 halves A re-read traffic vs BN=128 (4 N-blocks instead of 8).
// Workspace need: (32768+1024)*512*2 B = 33 MB.
// ---------------------------------------------------------------------------

typedef short short8 __attribute__((ext_vector_type(8)));
typedef float f32x16 __attribute__((ext_vector_type(16)));

#define KDIM 512
#define BK 64

__device__ __forceinline__ unsigned short f2bf(float f) {
  uint32_t u = __float_as_uint(f);
  u += 0x7FFFu + ((u >> 16) & 1u);   // round-to-nearest-even
  return (unsigned short)(u >> 16);
}

// One wave per row; fully coalesced (lane-adjacent float4 reads).
// Rows [0,M) from z; rows [M, M+Npad) map to cm (r >= Ncls writes zeros).
__global__ __launch_bounds__(256) void normalize_rows_kernel(
    const float* __restrict__ z, const float* __restrict__ cm,
    unsigned short* __restrict__ zn, unsigned short* __restrict__ bn,
    int M, int Ncls, int Npad) {
  int gr = blockIdx.x * 4 + (threadIdx.x >> 6);
  int lane = threadIdx.x & 63;

  const float* src;
  unsigned short* dst;
  bool zero = false;
  if (gr < M) {
    src = z + (size_t)gr * KDIM;
    dst = zn + (size_t)gr * KDIM;
  } else {
    int r = gr - M;
    if (r >= Npad) return;
    dst = bn + (size_t)r * KDIM;
    zero = (r >= Ncls);
    src = cm + (size_t)(zero ? 0 : r) * KDIM;
  }

  if (zero) {
    uint2 zv = make_uint2(0u, 0u);
    *(uint2*)(dst + lane * 4) = zv;
    *(uint2*)(dst + 256 + lane * 4) = zv;
    return;
  }

  const float4* s4 = (const float4*)src;
  float4 x0 = s4[lane];        // elements [4*lane, 4*lane+4)
  float4 x1 = s4[lane + 64];   // elements [256+4*lane, ...)
  float s = x0.x * x0.x + x0.y * x0.y + x0.z * x0.z + x0.w * x0.w +
            x1.x * x1.x + x1.y * x1.y + x1.z * x1.z + x1.w * x1.w;
#pragma unroll
  for (int off = 32; off > 0; off >>= 1) s += __shfl_xor(s, off, 64);
  float scale = 1.0f / fmaxf(sqrtf(s), 1e-8f);

  union { unsigned short u[4]; uint2 v; } p0, p1;
  p0.u[0] = f2bf(x0.x * scale); p0.u[1] = f2bf(x0.y * scale);
  p0.u[2] = f2bf(x0.z * scale); p0.u[3] = f2bf(x0.w * scale);
  p1.u[0] = f2bf(x1.x * scale); p1.u[1] = f2bf(x1.y * scale);
  p1.u[2] = f2bf(x1.z * scale); p1.u[3] = f2bf(x1.w * scale);
  *(uint2*)(dst + lane * 4) = p0.v;
  *(uint2*)(dst + 256 + lane * 4) = p1.v;
}

// C = A * B^T. A: [M][512] bf16 bits, B: [Npad][512] bf16 bits, C: [M][Ncls] f32.
// 128x256 block tile, 8 waves in 2(M)x4(N), each wave 64x64 = 2x2 MFMA 32x32x16.
// LDS tiles [rows][8 units of 16B], unit' = unit ^ (row & 7) swizzle.
__global__ __launch_bounds__(512, 4) void gemm_bt_kernel(
    const unsigned short* __restrict__ A,
    const unsigned short* __restrict__ B,
    float* __restrict__ C, int M, int Ncls) {
  __shared__ unsigned short As[128 * BK];   // 16 KB
  __shared__ unsigned short Bs[256 * BK];   // 32 KB

  const int tid = threadIdx.x;
  const int wave = tid >> 6;
  const int lane = tid & 63;
  const int m0 = blockIdx.y * 128;
  const int n0 = blockIdx.x * 256;
  const int wm = (wave & 1) * 64;   // wave's M offset in tile
  const int wn = (wave >> 1) * 64;  // wave's N offset in tile (0..192)

  // ---- staging geometry --------------------------------------------------
  // Chunk = 8 rows x 64 cols (= 64 lanes x 16B). 16 A-chunks + 32 B-chunks
  // = 48 chunks over 8 waves -> 6 per wave. Lane l covers row l>>3, source
  // unit (l&7)^((l>>3)&7) so LDS holds unit' = u ^ (row&7).
  const int l3 = lane >> 3;                      // row within 8-row chunk
  const int su = (lane & 7) ^ (l3 & 7);          // source 16B-unit (0..7)
  const int lanev = l3 * KDIM + su * 8;          // per-lane global elem offset

  const unsigned short* gsrc[6];
  unsigned short* ldst[6];
#pragma unroll
  for (int c = 0; c < 6; ++c) {
    int ch = wave * 6 + c;
    if (ch < 16) {
      gsrc[c] = A + (size_t)(m0 + ch * 8) * KDIM + lanev;
      ldst[c] = &As[ch * 512 + lane * 8];
    } else {
      int cb = ch - 16;
      gsrc[c] = B + (size_t)(n0 + cb * 8) * KDIM + lanev;
      ldst[c] = &Bs[cb * 512 + lane * 8];
    }
  }

  // ---- fragment-read geometry -------------------------------------------
  const int fm = lane & 31;        // row within 32-row frag (A: m, B: n)
  const int kh = lane >> 5;        // k-half (0/1) -> 8-elem unit select
  const int fx = fm & 7;           // row phase for the XOR swizzle

  f32x16 acc[2][2] = {};

  for (int k0 = 0; k0 < KDIM; k0 += BK) {
    __syncthreads();  // previous iteration's LDS reads complete
#pragma unroll
    for (int c = 0; c < 6; ++c)
      __builtin_amdgcn_global_load_lds(
          (const __attribute__((address_space(1))) void*)(gsrc[c] + k0),
          (__attribute__((address_space(3))) void*)ldst[c], 16, 0, 0);
    __syncthreads();  // staged tiles visible

#pragma unroll
    for (int ks = 0; ks < 4; ++ks) {            // 4 k-steps of 16 within BK
      int u = ((ks << 1) | kh) ^ fx;            // swizzled unit
      short8 a0 = *(const short8*)&As[(wm + fm) * BK + u * 8];
      short8 a1 = *(const short8*)&As[(wm + 32 + fm) * BK + u * 8];
      short8 b0 = *(const short8*)&Bs[(wn + fm) * BK + u * 8];
      short8 b1 = *(const short8*)&Bs[(wn + 32 + fm) * BK + u * 8];
      acc[0][0] = __builtin_amdgcn_mfma_f32_32x32x16_bf16(a0, b0, acc[0][0], 0, 0, 0);
      acc[0][1] = __builtin_amdgcn_mfma_f32_32x32x16_bf16(a0, b1, acc[0][1], 0, 0, 0);
      acc[1][0] = __builtin_amdgcn_mfma_f32_32x32x16_bf16(a1, b0, acc[1][0], 0, 0, 0);
      acc[1][1] = __builtin_amdgcn_mfma_f32_32x32x16_bf16(a1, b1, acc[1][1], 0, 0, 0);
    }
  }

  // C/D layout (32x32): col = lane&31, row = (reg&3) + 8*(reg>>2) + 4*(lane>>5)
  const int cn = lane & 31;
  const int ch4 = (lane >> 5) * 4;
#pragma unroll
  for (int mi = 0; mi < 2; ++mi) {
#pragma unroll
    for (int ni = 0; ni < 2; ++ni) {
      int n = n0 + wn + ni * 32 + cn;
      if (n < Ncls) {
        size_t base = (size_t)(m0 + wm + mi * 32 + ch4) * (size_t)Ncls + n;
#pragma unroll
        for (int r = 0; r < 16; ++r) {
          int row = (r & 3) + 8 * (r >> 2);
          C[base + (size_t)row * Ncls] = acc[mi][ni][r];
        }
      }
    }
  }
}

extern "C" void kernel_launch(void* const* d_in, const int* in_sizes, int n_in,
                              void* d_out, int out_size, void* d_ws, size_t ws_size,
                              hipStream_t stream) {
  const float* z  = (const float*)d_in[0];
  const float* cm = (const float*)d_in[1];
  float* out = (float*)d_out;

  const int M    = in_sizes[0] / KDIM;                 // 32768
  const int Ncls = in_sizes[1] / KDIM;                 // 1001
  const int Npad = ((Ncls + 255) / 256) * 256;         // 1024

  unsigned short* zn = (unsigned short*)d_ws;
  unsigned short* bn = zn + (size_t)M * KDIM;

  int nblk = (M + Npad + 3) / 4;  // one wave per row, 4 waves per block
  normalize_rows_kernel<<<nblk, 256, 0, stream>>>(z, cm, zn, bn, M, Ncls, Npad);

  dim3 grid(Npad / 256, M / 128);
  gemm_bt_kernel<<<grid, 512, 0, stream>>>(zn, bn, out, M, Ncls);
}

// Round 4
// 220.256 us; speedup vs baseline: 1.2060x; 1.0870x over previous
//
#include <hip/hip_runtime.h>
#include <hip/hip_bf16.h>
#include <stdint.h>

// ---------------------------------------------------------------------------
// Cosine similarity: C[n][m] = <z_n/||z_n||, cm_m/||cm_m||>
// M=32768 rows z, Ncls=1001 rows cm, K=512, out fp32 [M][Ncls].
// Pass 1 (tiny): normalize cm rows -> bf16 bn [Npad=1024][512] in d_ws.
// Pass 2 (fused): GEMM C = bf16(z) * bn^T scaled by 1/||z_row||.
//   - A (z) staged fp32 global -> VGPR (prefetched across the barrier,
//     hidden under MFMA) -> f2bf convert -> ds_write_b128 into the same
//     XOR-swizzled bf16 LDS layout as before. Row norms accumulated from
//     the fp32 values in registers (free), reduced once after the K-loop.
//   - B staged async via global_load_lds x16 (bf16, unchanged).
//   - 128M x 256N tile, 512 thr (8 waves of 64x64 = 2x2 mfma_32x32x16), BK=64.
// Workspace need: 1024*512*2 B = 1 MB.
// ---------------------------------------------------------------------------

typedef short short8 __attribute__((ext_vector_type(8)));
typedef float f32x16 __attribute__((ext_vector_type(16)));

#define KDIM 512
#define BK 64

__device__ __forceinline__ unsigned short f2bf(float f) {
  uint32_t u = __float_as_uint(f);
  u += 0x7FFFu + ((u >> 16) & 1u);   // round-to-nearest-even
  return (unsigned short)(u >> 16);
}

// One wave per cm row; rows >= Ncls written as zeros (GEMM B-side pad).
__global__ __launch_bounds__(256) void normalize_cm_kernel(
    const float* __restrict__ cm, unsigned short* __restrict__ bn,
    int Ncls, int Npad) {
  int r = blockIdx.x * 4 + (threadIdx.x >> 6);
  int lane = threadIdx.x & 63;
  if (r >= Npad) return;
  unsigned short* dst = bn + (size_t)r * KDIM;
  if (r >= Ncls) {
    uint2 zv = make_uint2(0u, 0u);
    *(uint2*)(dst + lane * 4) = zv;
    *(uint2*)(dst + 256 + lane * 4) = zv;
    return;
  }
  const float4* s4 = (const float4*)(cm + (size_t)r * KDIM);
  float4 x0 = s4[lane];
  float4 x1 = s4[lane + 64];
  float s = x0.x * x0.x + x0.y * x0.y + x0.z * x0.z + x0.w * x0.w +
            x1.x * x1.x + x1.y * x1.y + x1.z * x1.z + x1.w * x1.w;
#pragma unroll
  for (int off = 32; off > 0; off >>= 1) s += __shfl_xor(s, off, 64);
  float scale = 1.0f / fmaxf(sqrtf(s), 1e-8f);

  union { unsigned short u[4]; uint2 v; } p0, p1;
  p0.u[0] = f2bf(x0.x * scale); p0.u[1] = f2bf(x0.y * scale);
  p0.u[2] = f2bf(x0.z * scale); p0.u[3] = f2bf(x0.w * scale);
  p1.u[0] = f2bf(x1.x * scale); p1.u[1] = f2bf(x1.y * scale);
  p1.u[2] = f2bf(x1.z * scale); p1.u[3] = f2bf(x1.w * scale);
  *(uint2*)(dst + lane * 4) = p0.v;
  *(uint2*)(dst + 256 + lane * 4) = p1.v;
}

// Fused: C = bf16(Z) * B^T, rows scaled by 1/max(||Z_row||, 1e-8).
// Z: [M][512] fp32, B: [Npad][512] bf16 bits, C: [M][Ncls] f32.
__global__ __launch_bounds__(512, 4) void gemm_fused_kernel(
    const float* __restrict__ Z,
    const unsigned short* __restrict__ B,
    float* __restrict__ C, int M, int Ncls) {
  __shared__ unsigned short As[128 * BK];   // 16 KB (bf16)
  __shared__ unsigned short Bs[256 * BK];   // 32 KB (bf16)
  __shared__ float ns[128];                 // row ||z||^2

  const int tid = threadIdx.x;
  const int wave = tid >> 6;
  const int lane = tid & 63;
  const int m0 = blockIdx.y * 128;
  const int n0 = blockIdx.x * 256;
  const int wm = (wave & 1) * 64;   // wave's M offset
  const int wn = (wave >> 1) * 64;  // wave's N offset (0..192)

  // Chunk = 8 rows x 64 cols. Lane l: row l>>3, source unit (l&7)^((l>>3)&7)
  // so LDS holds unit' = u ^ (row&7) (conflict-free swizzle, same as R3).
  const int l3 = lane >> 3;
  const int su = (lane & 7) ^ (l3 & 7);

  // A: 2 chunks per wave (16 chunks of the 128-row tile), fp32 source.
  const int chA = wave * 2;
  const float* Ag0 = Z + (size_t)(m0 + chA * 8 + l3) * KDIM + su * 8;
  const float* Ag1 = Z + (size_t)(m0 + (chA + 1) * 8 + l3) * KDIM + su * 8;
  unsigned short* Al0 = &As[chA * 512 + lane * 8];
  unsigned short* Al1 = &As[(chA + 1) * 512 + lane * 8];

  // B: 4 chunks per wave (32 chunks of the 256-row tile), async bf16.
  const unsigned short* Bgp[4];
  unsigned short* Blp[4];
#pragma unroll
  for (int c = 0; c < 4; ++c) {
    int cb = wave * 4 + c;
    Bgp[c] = B + (size_t)(n0 + cb * 8 + l3) * KDIM + su * 8;
    Blp[c] = &Bs[cb * 512 + lane * 8];
  }

  const int fm = lane & 31;        // fragment row (A: m, B: n)
  const int kh = lane >> 5;        // k-half
  const int fx = fm & 7;           // swizzle phase

  f32x16 acc[2][2] = {};
  float rs0 = 0.0f, rs1 = 0.0f;    // per-thread partial row ssq

  // Prologue: prefetch A slice k0=0 into registers.
  float4 p00 = *(const float4*)(Ag0);
  float4 p01 = *(const float4*)(Ag0 + 4);
  float4 p10 = *(const float4*)(Ag1);
  float4 p11 = *(const float4*)(Ag1 + 4);

  for (int k0 = 0; k0 < KDIM; k0 += BK) {
    __syncthreads();  // previous iteration's LDS reads complete
#pragma unroll
    for (int c = 0; c < 4; ++c)
      __builtin_amdgcn_global_load_lds(
          (const __attribute__((address_space(1))) void*)(Bgp[c] + k0),
          (__attribute__((address_space(3))) void*)Blp[c], 16, 0, 0);

    // Convert prefetched A (fp32->bf16), accumulate norms, stage to LDS.
    rs0 += p00.x * p00.x + p00.y * p00.y + p00.z * p00.z + p00.w * p00.w +
           p01.x * p01.x + p01.y * p01.y + p01.z * p01.z + p01.w * p01.w;
    rs1 += p10.x * p10.x + p10.y * p10.y + p10.z * p10.z + p10.w * p10.w +
           p11.x * p11.x + p11.y * p11.y + p11.z * p11.z + p11.w * p11.w;
    union { unsigned short u[8]; uint4 v; } pk;
    pk.u[0] = f2bf(p00.x); pk.u[1] = f2bf(p00.y);
    pk.u[2] = f2bf(p00.z); pk.u[3] = f2bf(p00.w);
    pk.u[4] = f2bf(p01.x); pk.u[5] = f2bf(p01.y);
    pk.u[6] = f2bf(p01.z); pk.u[7] = f2bf(p01.w);
    *(uint4*)Al0 = pk.v;
    pk.u[0] = f2bf(p10.x); pk.u[1] = f2bf(p10.y);
    pk.u[2] = f2bf(p10.z); pk.u[3] = f2bf(p10.w);
    pk.u[4] = f2bf(p11.x); pk.u[5] = f2bf(p11.y);
    pk.u[6] = f2bf(p11.z); pk.u[7] = f2bf(p11.w);
    *(uint4*)Al1 = pk.v;

    __syncthreads();  // staged tiles visible (drains B vmcnt + A lgkm)

    // Prefetch next A slice into registers; latency hides under MFMA.
    int k1 = k0 + BK;
    if (k1 < KDIM) {
      p00 = *(const float4*)(Ag0 + k1);
      p01 = *(const float4*)(Ag0 + k1 + 4);
      p10 = *(const float4*)(Ag1 + k1);
      p11 = *(const float4*)(Ag1 + k1 + 4);
    }

#pragma unroll
    for (int ks = 0; ks < 4; ++ks) {
      int u = ((ks << 1) | kh) ^ fx;
      short8 a0 = *(const short8*)&As[(wm + fm) * BK + u * 8];
      short8 a1 = *(const short8*)&As[(wm + 32 + fm) * BK + u * 8];
      short8 b0 = *(const short8*)&Bs[(wn + fm) * BK + u * 8];
      short8 b1 = *(const short8*)&Bs[(wn + 32 + fm) * BK + u * 8];
      acc[0][0] = __builtin_amdgcn_mfma_f32_32x32x16_bf16(a0, b0, acc[0][0], 0, 0, 0);
      acc[0][1] = __builtin_amdgcn_mfma_f32_32x32x16_bf16(a0, b1, acc[0][1], 0, 0, 0);
      acc[1][0] = __builtin_amdgcn_mfma_f32_32x32x16_bf16(a1, b0, acc[1][0], 0, 0, 0);
      acc[1][1] = __builtin_amdgcn_mfma_f32_32x32x16_bf16(a1, b1, acc[1][1], 0, 0, 0);
    }
  }

  // Finish row norms: reduce across the 8 lanes sharing each row, publish.
#pragma unroll
  for (int off = 1; off < 8; off <<= 1) {
    rs0 += __shfl_xor(rs0, off, 64);
    rs1 += __shfl_xor(rs1, off, 64);
  }
  if ((lane & 7) == 0) {
    ns[chA * 8 + l3] = rs0;       // row of chunk chA
    ns[chA * 8 + 8 + l3] = rs1;   // row of chunk chA+1
  }
  __syncthreads();

  // Epilogue: C = acc * 1/max(||z_row||, eps).
  // C/D layout (32x32): col = lane&31, row = (r&3) + 8*(r>>2) + 4*(lane>>5).
  const int cn = lane & 31;
  const int ch4 = kh * 4;
#pragma unroll
  for (int mi = 0; mi < 2; ++mi) {
    float rn[16];
#pragma unroll
    for (int q = 0; q < 4; ++q) {
      float4 n4 = *(const float4*)&ns[wm + mi * 32 + q * 8 + ch4];
      rn[q * 4 + 0] = 1.0f / fmaxf(sqrtf(n4.x), 1e-8f);
      rn[q * 4 + 1] = 1.0f / fmaxf(sqrtf(n4.y), 1e-8f);
      rn[q * 4 + 2] = 1.0f / fmaxf(sqrtf(n4.z), 1e-8f);
      rn[q * 4 + 3] = 1.0f / fmaxf(sqrtf(n4.w), 1e-8f);
    }
#pragma unroll
    for (int ni = 0; ni < 2; ++ni) {
      int n = n0 + wn + ni * 32 + cn;
      if (n < Ncls) {
        size_t base = (size_t)(m0 + wm + mi * 32 + ch4) * (size_t)Ncls + n;
#pragma unroll
        for (int r = 0; r < 16; ++r) {
          int row = (r & 3) + 8 * (r >> 2);
          C[base + (size_t)row * Ncls] = acc[mi][ni][r] * rn[r];
        }
      }
    }
  }
}

extern "C" void kernel_launch(void* const* d_in, const int* in_sizes, int n_in,
                              void* d_out, int out_size, void* d_ws, size_t ws_size,
                              hipStream_t stream) {
  const float* z  = (const float*)d_in[0];
  const float* cm = (const float*)d_in[1];
  float* out = (float*)d_out;

  const int M    = in_sizes[0] / KDIM;                 // 32768
  const int Ncls = in_sizes[1] / KDIM;                 // 1001
  const int Npad = ((Ncls + 255) / 256) * 256;         // 1024

  unsigned short* bn = (unsigned short*)d_ws;          // 1 MB

  normalize_cm_kernel<<<Npad / 4, 256, 0, stream>>>(cm, bn, Ncls, Npad);

  dim3 grid(Npad / 256, M / 128);
  gemm_fused_kernel<<<grid, 512, 0, stream>>>(z, bn, out, M, Ncls);
}